// Round 8
// baseline (189.038 us; speedup 1.0000x reference)
//
#include <hip/hip_runtime.h>
#include <hip/hip_bf16.h>

#define NB 64
#define NL 512
#define NH 768
#define NT 9

#define LOG2E 1.4426950408889634f
#define LN2   0.6931471805599453f
#define NEG_INF -1e30f

#if defined(__has_builtin)
#if __has_builtin(__builtin_amdgcn_exp2f)
#define EXP2F(x) __builtin_amdgcn_exp2f(x)
#else
#define EXP2F(x) exp2f(x)
#endif
#if __has_builtin(__builtin_amdgcn_logf)
#define LOG2F(x) __builtin_amdgcn_logf(x)
#else
#define LOG2F(x) log2f(x)
#endif
#else
#define EXP2F(x) exp2f(x)
#define LOG2F(x) log2f(x)
#endif

// ---------------------------------------------------------------------------
// Kernel A: logits = hidden @ W + b  ->  out+1 and d_ws (aligned mirror).
// W held in REGISTERS: each lane owns k-slice {4*(lane+64i)+m}, 12 k-rows x 9
// = 108 floats, preloaded once from an LDS linear copy. Per row-pair: 6
// float4 global loads + 216 FMA + 99 cross-lane ops. No per-row W ds_reads.
// Expect HBM-bound (~100 MB reads @ >80% of 6.3 TB/s).
// ---------------------------------------------------------------------------
__global__ __launch_bounds__(256) void gemm_kernel(
    const float* __restrict__ hidden, const float* __restrict__ W,
    const float* __restrict__ bias, float* __restrict__ out,
    float* __restrict__ ws)
{
  __shared__ __align__(16) float w_lds[NH * NT];  // 6912 floats, 27.6 KB
  const int tid = threadIdx.x;
  for (int idx = tid; idx < NH * NT / 4; idx += 256)
    reinterpret_cast<float4*>(w_lds)[idx] = reinterpret_cast<const float4*>(W)[idx];
  if (blockIdx.x == 0 && tid == 0) out[0] = 0.0f;
  __syncthreads();

  const int lane = tid & 63;
  const int wv = blockIdx.x * 4 + (tid >> 6);  // 0..4095
  const int jj = (lane < 32) ? lane : lane - 32;
  const float bx = (jj < NT) ? bias[jj] : 0.0f;

  // preload W slice into registers: wreg[i][m][j], k = 4*(lane+64i)+m
  float wreg[3][4][NT];
#pragma unroll
  for (int i = 0; i < 3; ++i) {
#pragma unroll
    for (int m = 0; m < 4; ++m) {
      const float* wl = &w_lds[(4 * (lane + 64 * i) + m) * NT];
#pragma unroll
      for (int j = 0; j < NT; ++j) wreg[i][m][j] = wl[j];
    }
  }

  for (int p = wv; p < NB * NL / 2; p += 4096) {
    const float4* hp0 = reinterpret_cast<const float4*>(hidden + (size_t)(2 * p) * NH);
    const float4* hp1 = reinterpret_cast<const float4*>(hidden + (size_t)(2 * p + 1) * NH);
    float4 a[3], b[3];
#pragma unroll
    for (int i = 0; i < 3; ++i) a[i] = hp0[lane + 64 * i];
#pragma unroll
    for (int i = 0; i < 3; ++i) b[i] = hp1[lane + 64 * i];

    float acc0[NT], acc1[NT];
#pragma unroll
    for (int j = 0; j < NT; ++j) { acc0[j] = 0.0f; acc1[j] = 0.0f; }
#pragma unroll
    for (int i = 0; i < 3; ++i) {
#pragma unroll
      for (int m = 0; m < 4; ++m) {
        const float ha = (m == 0) ? a[i].x : (m == 1) ? a[i].y : (m == 2) ? a[i].z : a[i].w;
        const float hb = (m == 0) ? b[i].x : (m == 1) ? b[i].y : (m == 2) ? b[i].z : b[i].w;
#pragma unroll
        for (int j = 0; j < NT; ++j) {
          acc0[j] = fmaf(ha, wreg[i][m][j], acc0[j]);
          acc1[j] = fmaf(hb, wreg[i][m][j], acc1[j]);
        }
      }
    }
    // butterfly within 32-lane halves (offsets 1..16)
#pragma unroll
    for (int off = 1; off <= 16; off <<= 1) {
#pragma unroll
      for (int j = 0; j < NT; ++j) {
        acc0[j] += __shfl_xor(acc0[j], off);
        acc1[j] += __shfl_xor(acc1[j], off);
      }
    }
    // final stage: lanes<32 finish row0, lanes>=32 finish row1
    float tot[NT];
#pragma unroll
    for (int j = 0; j < NT; ++j) {
      const float xsel = (lane < 32) ? acc1[j] : acc0[j];
      const float other = __shfl_xor(xsel, 32);
      tot[j] = ((lane < 32) ? acc0[j] : acc1[j]) + other;
    }
    float v = tot[0];
#pragma unroll
    for (int j = 1; j < NT; ++j)
      if (jj == j) v = tot[j];
    v += bx;
    if (lane < NT) {
      const size_t o = (size_t)(2 * p) * NT + jj;
      out[1 + o] = v;
      ws[o] = v;
    } else if (lane >= 32 && jj < NT) {
      const size_t o = (size_t)(2 * p + 1) * NT + jj;
      out[1 + o] = v;
      ws[o] = v;
    }
  }
}

// ---------------------------------------------------------------------------
// Kernel B: per-batch CRF NLL. One block per batch (576 threads).
// Reads the 16B-aligned logits mirror from d_ws (float4 staging).
// ---------------------------------------------------------------------------
#define NC 32
#define CS 16

__global__ __launch_bounds__(576) void crf_kernel(
    const float* __restrict__ logits_ws,
    const int* __restrict__ mask, const int* __restrict__ labels,
    const float* __restrict__ start_trans, const float* __restrict__ end_trans,
    const float* __restrict__ trans, float* __restrict__ loss_out)
{
  const int b = blockIdx.x;
  const int tid = threadIdx.x;

  __shared__ __align__(16) float lg[NL * NT];  // 4608 floats
  __shared__ float trans_s[NT * NT];
  __shared__ float E_s[NT * NT];
  __shared__ int mask_s[NL];
  __shared__ float P[NC * NT * NT];
  __shared__ float red_num[9];
  __shared__ float red_cnt[9];

  const float4* lgg4 = reinterpret_cast<const float4*>(logits_ws + (size_t)b * NL * NT);
#pragma unroll
  for (int r = 0; r < 2; ++r)
    reinterpret_cast<float4*>(lg)[tid + 576 * r] = lgg4[tid + 576 * r];
  if (tid < NT * NT) {
    float tv = trans[tid];
    trans_s[tid] = tv;
    E_s[tid] = EXP2F(tv * LOG2E);
  }
  if (tid < NL) mask_s[tid] = mask[b * NL + tid];
  __syncthreads();

  // ---- numerator partials (threads 0..511 = timestep t) ----
  float numpart = 0.0f, cntpart = 0.0f;
  if (tid < NL) {
    int lab = labels[b * NL + tid];
    if (lab == -100) lab = 0;
    if (tid == 0) {
      numpart = start_trans[lab] + lg[lab];
    } else {
      int labp = labels[b * NL + tid - 1];
      if (labp == -100) labp = 0;
      float mf = (float)mask_s[tid];
      numpart = mf * (trans_s[labp * NT + lab] + lg[tid * NT + lab]);
    }
    cntpart = (float)mask_s[tid];
  }
#pragma unroll
  for (int off = 32; off >= 1; off >>= 1) {
    numpart += __shfl_down(numpart, off);
    cntpart += __shfl_down(cntpart, off);
  }
  if ((tid & 63) == 0) {
    red_num[tid >> 6] = numpart;
    red_cnt[tid >> 6] = cntpart;
  }

  // ---- phase 1: chunk matrix products ----
  if (tid < NC * NT) {
    const int c = tid / NT;
    const int i = tid - c * NT;
    float Er[NT * NT];
#pragma unroll
    for (int kj = 0; kj < NT * NT; ++kj) Er[kj] = E_s[kj];
    float run[NT];
    const int t0 = 1 + CS * c;
    if (mask_s[t0]) {
#pragma unroll
      for (int j = 0; j < NT; ++j) run[j] = trans_s[i * NT + j] + lg[t0 * NT + j];
    } else {
#pragma unroll
      for (int j = 0; j < NT; ++j) run[j] = (i == j) ? 0.0f : NEG_INF;
    }
    const int tend = min(t0 + CS, NL);
    for (int t = t0 + 1; t < tend; ++t) {
      if (!mask_s[t]) continue;
      float m = run[0];
#pragma unroll
      for (int k = 1; k < NT; ++k) m = fmaxf(m, run[k]);
      float p[NT];
#pragma unroll
      for (int k = 0; k < NT; ++k) p[k] = EXP2F((run[k] - m) * LOG2E);
      float dot[NT];
#pragma unroll
      for (int j = 0; j < NT; ++j) dot[j] = 0.0f;
#pragma unroll
      for (int k = 0; k < NT; ++k) {
#pragma unroll
        for (int j = 0; j < NT; ++j) dot[j] = fmaf(p[k], Er[k * NT + j], dot[j]);
      }
#pragma unroll
      for (int j = 0; j < NT; ++j)
        run[j] = fmaf(LOG2F(dot[j]), LN2, m) + lg[t * NT + j];
    }
#pragma unroll
    for (int j = 0; j < NT; ++j) P[c * (NT * NT) + i * NT + j] = run[j];
  }
  __syncthreads();

  // ---- phase 2: fold chunk matrices into init vector (wave 0 only) ----
  if (tid < 64) {
    const int j = tid;
    const int jj = (j < NT) ? j : 0;
    float v = (j < NT) ? (start_trans[j] + lg[j]) : NEG_INF;
    for (int c = 0; c < NC; ++c) {
      float s[NT];
#pragma unroll
      for (int i = 0; i < NT; ++i)
        s[i] = __shfl(v, i) + P[c * (NT * NT) + i * NT + jj];
      float m = s[0];
#pragma unroll
      for (int i = 1; i < NT; ++i) m = fmaxf(m, s[i]);
      float sum = 0.0f;
#pragma unroll
      for (int i = 0; i < NT; ++i) sum += EXP2F((s[i] - m) * LOG2E);
      v = fmaf(LOG2F(sum), LN2, m);
    }
    float x = (j < NT) ? (v + end_trans[j]) : NEG_INF;
    float m = x;
#pragma unroll
    for (int off = 32; off >= 1; off >>= 1) m = fmaxf(m, __shfl_xor(m, off));
    float e = (j < NT) ? EXP2F((x - m) * LOG2E) : 0.0f;
#pragma unroll
    for (int off = 32; off >= 1; off >>= 1) e += __shfl_xor(e, off);
    if (tid == 0) {
      float denom = fmaf(LOG2F(e), LN2, m);
      float num = 0.0f, cnt = 0.0f;
#pragma unroll
      for (int w = 0; w < 9; ++w) {
        num += red_num[w];
        cnt += red_cnt[w];
      }
      int seq_end = (int)cnt - 1;
      int lastlab = labels[b * NL + seq_end];
      if (lastlab == -100) lastlab = 0;
      num += end_trans[lastlab];
      float llh = num - denom;
      atomicAdd(loss_out, -llh * (1.0f / NB));
    }
  }
}

extern "C" void kernel_launch(void* const* d_in, const int* in_sizes, int n_in,
                              void* d_out, int out_size, void* d_ws, size_t ws_size,
                              hipStream_t stream) {
  const float* hidden      = (const float*)d_in[0];
  const int*   attn_mask   = (const int*)d_in[1];
  const int*   labels      = (const int*)d_in[2];
  const float* W           = (const float*)d_in[3];
  const float* bias        = (const float*)d_in[4];
  const float* start_trans = (const float*)d_in[5];
  const float* end_trans   = (const float*)d_in[6];
  const float* trans       = (const float*)d_in[7];
  float* out = (float*)d_out;
  float* ws  = (float*)d_ws;

  hipLaunchKernelGGL(gemm_kernel, dim3(1024), dim3(256), 0, stream,
                     hidden, W, bias, out, ws);
  hipLaunchKernelGGL(crf_kernel, dim3(64), dim3(576), 0, stream,
                     ws, attn_mask, labels, start_trans, end_trans, trans, out);
}